// Round 1
// baseline (291.518 us; speedup 1.0000x reference)
//
#include <hip/hip_runtime.h>
#include <math.h>

#define NN 8
#define CC 4
#define FF 257
#define TT 2000
#define BB 8
#define MM 80
#define EPSF 1e-5f
#define VSTR 261   // odd stride -> conflict-free LDS (261 % 32 = 5, coprime)

// ---------------- kernel 1: beamform q,k and reduce s[n,b] ----------------
__global__ __launch_bounds__(256) void k_beam_s(
    const float* __restrict__ xr_g, const float* __restrict__ xi_g,
    const float* __restrict__ wq_r, const float* __restrict__ wq_i,
    const float* __restrict__ wk_r, const float* __restrict__ wk_i,
    float* __restrict__ s_buf)
{
    int nf = blockIdx.x;
    int n = nf / FF, f = nf % FF;
    int t = blockIdx.y * 256 + threadIdx.x;

    // f is block-uniform -> these become scalar loads
    float qwr[CC], qwi[CC];
#pragma unroll
    for (int c = 0; c < CC; ++c) { qwr[c] = wq_r[f*CC + c]; qwi[c] = wq_i[f*CC + c]; }

    float part[BB];
#pragma unroll
    for (int b = 0; b < BB; ++b) part[b] = 0.f;

    if (t < TT) {
        float xr[CC], xi[CC];
#pragma unroll
        for (int c = 0; c < CC; ++c) {
            xr[c] = xr_g[((n*CC + c)*FF + f)*TT + t];
            xi[c] = xi_g[((n*CC + c)*FF + f)*TT + t];
        }
        float qr = 0.f, qi = 0.f;
#pragma unroll
        for (int c = 0; c < CC; ++c) {
            qr += xr[c]*qwr[c] - xi[c]*qwi[c];
            qi += xi[c]*qwr[c] + xr[c]*qwi[c];
        }
        float bq = sqrtf(qr*qr + qi*qi + EPSF);
#pragma unroll
        for (int b = 0; b < BB; ++b) {
            float kr = 0.f, ki = 0.f;
#pragma unroll
            for (int c = 0; c < CC; ++c) {
                float wr = wk_r[(f*BB + b)*CC + c];
                float wi = wk_i[(f*BB + b)*CC + c];
                kr += xr[c]*wr - xi[c]*wi;
                ki += xi[c]*wr + xr[c]*wi;
            }
            part[b] = bq * sqrtf(kr*kr + ki*ki + EPSF);
        }
    }

    __shared__ float red[4][BB];
    int lane = threadIdx.x & 63, wv = threadIdx.x >> 6;
#pragma unroll
    for (int b = 0; b < BB; ++b) {
        float v = part[b];
#pragma unroll
        for (int m = 32; m >= 1; m >>= 1) v += __shfl_xor(v, m);
        if (lane == 0) red[wv][b] = v;
    }
    __syncthreads();
    if (threadIdx.x < BB) {
        float v = red[0][threadIdx.x] + red[1][threadIdx.x]
                + red[2][threadIdx.x] + red[3][threadIdx.x];
        atomicAdd(&s_buf[n*BB + threadIdx.x], v);
    }
}

// ---------------- kernel 2: softmax over B per n ----------------
__global__ void k_softmax(const float* __restrict__ s_buf, float* __restrict__ w_buf)
{
    int tid = threadIdx.x;
    if (tid < NN*BB) {
        float v = s_buf[tid] * (1.0f / TT);
        float mx = v;
#pragma unroll
        for (int m = 4; m >= 1; m >>= 1) mx = fmaxf(mx, __shfl_xor(mx, m));
        float e = expf(v - mx);
        float sm = e;
#pragma unroll
        for (int m = 4; m >= 1; m >>= 1) sm += __shfl_xor(sm, m);
        w_buf[tid] = e / sm;
    }
}

// ---------------- kernel 2b: repack proj_w into padded stride-260 ----------------
__global__ void k_prep(const float* __restrict__ proj_w, float* __restrict__ proj_pad)
{
    int i = blockIdx.x * 256 + threadIdx.x;
    if (i < MM * 260) {
        int m = i / 260, f = i % 260;
        proj_pad[i] = (f < FF) ? proj_w[m*FF + f] : 0.f;
    }
}

// ---------------- kernel 3: v = sum_b w_b*bv, project, relu, log, BN partials ----------------
__global__ __launch_bounds__(256) void k_vproj(
    const float* __restrict__ xr_g, const float* __restrict__ xi_g,
    const float* __restrict__ wv_r, const float* __restrict__ wv_i,
    const float* __restrict__ w_buf, const float* __restrict__ proj_pad,
    float* __restrict__ out, double* __restrict__ bn_sum, double* __restrict__ bn_sumsq)
{
    __shared__ float v_lds[32 * VSTR];
    int bx = blockIdx.x;
    int n = bx / 63, chunk = bx % 63;
    int t0 = chunk * 32;

    float wn[BB];
#pragma unroll
    for (int b = 0; b < BB; ++b) wn[b] = w_buf[n*BB + b];

    int tl = threadIdx.x & 31, fg = threadIdx.x >> 5;
    int t = t0 + tl;
    bool tvalid = (t < TT);

    // stage A: fill v tile [32][261]
#pragma unroll 1
    for (int k = 0; k <= 32; ++k) {
        int f = fg + 8*k;
        if (f < 261) {
            float v = 0.f;
            if (f < FF && tvalid) {
                float xr[CC], xi[CC];
#pragma unroll
                for (int c = 0; c < CC; ++c) {
                    xr[c] = xr_g[((n*CC + c)*FF + f)*TT + t];
                    xi[c] = xi_g[((n*CC + c)*FF + f)*TT + t];
                }
#pragma unroll
                for (int b = 0; b < BB; ++b) {
                    const float4 wr4 = *reinterpret_cast<const float4*>(&wv_r[(f*BB + b)*CC]);
                    const float4 wi4 = *reinterpret_cast<const float4*>(&wv_i[(f*BB + b)*CC]);
                    float vr = xr[0]*wr4.x + xr[1]*wr4.y + xr[2]*wr4.z + xr[3]*wr4.w
                             - (xi[0]*wi4.x + xi[1]*wi4.y + xi[2]*wi4.z + xi[3]*wi4.w);
                    float vi = xi[0]*wr4.x + xi[1]*wr4.y + xi[2]*wr4.z + xi[3]*wr4.w
                             + xr[0]*wi4.x + xr[1]*wi4.y + xr[2]*wi4.z + xr[3]*wi4.w;
                    v += wn[b] * sqrtf(vr*vr + vi*vi + EPSF);
                }
            }
            v_lds[tl*VSTR + f] = v;
        }
    }
    __syncthreads();

    // stage B: per-thread 10-m matvec over F
    int g = fg;
    float acc[10];
#pragma unroll
    for (int j = 0; j < 10; ++j) acc[j] = 0.f;
    const float* pp = proj_pad + g * 10 * 260;
#pragma unroll 4
    for (int f4 = 0; f4 < 260; f4 += 4) {
        float v0 = v_lds[tl*VSTR + f4 + 0];
        float v1 = v_lds[tl*VSTR + f4 + 1];
        float v2 = v_lds[tl*VSTR + f4 + 2];
        float v3 = v_lds[tl*VSTR + f4 + 3];
#pragma unroll
        for (int j = 0; j < 10; ++j) {
            float4 p = *reinterpret_cast<const float4*>(&pp[j*260 + f4]);
            acc[j] += v0*p.x + v1*p.y + v2*p.z + v3*p.w;
        }
    }

#pragma unroll
    for (int j = 0; j < 10; ++j) {
        int m = g*10 + j;
        float r = logf(fmaxf(acc[j], 0.f) + EPSF);
        float s1 = tvalid ? r : 0.f;
        float s2 = tvalid ? r*r : 0.f;
#pragma unroll
        for (int msk = 16; msk >= 1; msk >>= 1) {
            s1 += __shfl_xor(s1, msk);
            s2 += __shfl_xor(s2, msk);
        }
        if (tvalid) out[(n*TT + t)*MM + m] = r;
        if (tl == 0) {
            atomicAdd(&bn_sum[m], (double)s1);
            atomicAdd(&bn_sumsq[m], (double)s2);
        }
    }
}

// ---------------- kernel 4a: BN finalize ----------------
__global__ void k_bnprep(const double* __restrict__ bn_sum, const double* __restrict__ bn_sumsq,
                         const float* __restrict__ gamma, const float* __restrict__ beta,
                         float* __restrict__ scale, float* __restrict__ shift)
{
    int m = threadIdx.x;
    if (m < MM) {
        double inv = 1.0 / (double)(NN * TT);
        double mu = bn_sum[m] * inv;
        double var = bn_sumsq[m] * inv - mu * mu;
        float sc = gamma[m] * rsqrtf((float)var + EPSF);
        scale[m] = sc;
        shift[m] = beta[m] - (float)mu * sc;
    }
}

// ---------------- kernel 4b: BN apply in-place ----------------
__global__ __launch_bounds__(256) void k_bnapply(float* __restrict__ out,
                                                 const float* __restrict__ scale,
                                                 const float* __restrict__ shift)
{
    int i = blockIdx.x * 256 + threadIdx.x;
    if (i < NN*TT*MM) {
        int m = i % MM;
        out[i] = out[i] * scale[m] + shift[m];
    }
}

extern "C" void kernel_launch(void* const* d_in, const int* in_sizes, int n_in,
                              void* d_out, int out_size, void* d_ws, size_t ws_size,
                              hipStream_t stream)
{
    const float* x_real   = (const float*)d_in[0];
    const float* x_imag   = (const float*)d_in[1];
    const float* wq_r     = (const float*)d_in[2];
    const float* wq_i     = (const float*)d_in[3];
    const float* wk_r     = (const float*)d_in[4];
    const float* wk_i     = (const float*)d_in[5];
    const float* wv_r     = (const float*)d_in[6];
    const float* wv_i     = (const float*)d_in[7];
    const float* proj_w   = (const float*)d_in[8];
    const float* bn_gamma = (const float*)d_in[9];
    const float* bn_beta  = (const float*)d_in[10];
    float* out = (float*)d_out;

    float* fws      = (float*)d_ws;
    float* s_buf    = fws;            // 64 floats
    float* w_buf    = fws + 64;       // 64 floats
    float* scale    = fws + 128;      // 80 floats
    float* shift    = fws + 208;      // 80 floats
    double* bn_sum  = (double*)((char*)d_ws + 1152);  // 80 doubles
    double* bn_sumsq= (double*)((char*)d_ws + 1792);  // 80 doubles
    float* proj_pad = fws + 608;      // 80*260 floats, byte offset 2432

    hipMemsetAsync(d_ws, 0, 2432, stream);

    k_prep<<<(MM*260 + 255)/256, 256, 0, stream>>>(proj_w, proj_pad);

    dim3 g1(NN*FF, 8);
    k_beam_s<<<g1, 256, 0, stream>>>(x_real, x_imag, wq_r, wq_i, wk_r, wk_i, s_buf);

    k_softmax<<<1, 64, 0, stream>>>(s_buf, w_buf);

    k_vproj<<<NN*63, 256, 0, stream>>>(x_real, x_imag, wv_r, wv_i, w_buf, proj_pad,
                                       out, bn_sum, bn_sumsq);

    k_bnprep<<<1, 128, 0, stream>>>(bn_sum, bn_sumsq, bn_gamma, bn_beta, scale, shift);

    k_bnapply<<<(NN*TT*MM + 255)/256, 256, 0, stream>>>(out, scale, shift);
}

// Round 2
// 167.653 us; speedup vs baseline: 1.7388x; 1.7388x over previous
//
#include <hip/hip_runtime.h>
#include <math.h>

#define NN 8
#define CC 4
#define FF 257
#define TT 2000
#define BB 8
#define MM 80
#define EPSF 1e-5f
#define VSTR 261   // odd stride -> conflict-free LDS (261 % 32 = 5, coprime with 32)
#define T4N 500    // TT/4

// ---------------- kernel 1: beamform q,k and reduce s partials ----------------
// grid (NN*FF, 2), block 256. Each thread: 4 consecutive t via float4.
__global__ __launch_bounds__(256) void k_beam_s(
    const float* __restrict__ xr_g, const float* __restrict__ xi_g,
    const float* __restrict__ wq_r, const float* __restrict__ wq_i,
    const float* __restrict__ wk_r, const float* __restrict__ wk_i,
    float* __restrict__ s_buf)
{
    int nf = blockIdx.x;
    int n = nf / FF, f = nf % FF;
    int t4 = blockIdx.y * 256 + threadIdx.x;

    float part[BB];
#pragma unroll
    for (int b = 0; b < BB; ++b) part[b] = 0.f;

    if (t4 < T4N) {
        const float* xr_base = xr_g + ((size_t)(n*CC)*FF + f) * TT + t4*4;
        const float* xi_base = xi_g + ((size_t)(n*CC)*FF + f) * TT + t4*4;
        float4 xr4[CC], xi4[CC];
#pragma unroll
        for (int c = 0; c < CC; ++c) {
            xr4[c] = *reinterpret_cast<const float4*>(xr_base + (size_t)c*FF*TT);
            xi4[c] = *reinterpret_cast<const float4*>(xi_base + (size_t)c*FF*TT);
        }
        const float* xrp = (const float*)xr4;
        const float* xip = (const float*)xi4;

        float bq[4];
#pragma unroll
        for (int tt = 0; tt < 4; ++tt) {
            float qr = 0.f, qi = 0.f;
#pragma unroll
            for (int c = 0; c < CC; ++c) {
                float xr = xrp[c*4 + tt], xi = xip[c*4 + tt];
                float wr = wq_r[f*CC + c], wi = wq_i[f*CC + c];  // f uniform -> scalar
                qr += xr*wr - xi*wi;
                qi += xi*wr + xr*wi;
            }
            bq[tt] = sqrtf(qr*qr + qi*qi + EPSF);
        }
#pragma unroll
        for (int b = 0; b < BB; ++b) {
            float acc = 0.f;
#pragma unroll
            for (int tt = 0; tt < 4; ++tt) {
                float kr = 0.f, ki = 0.f;
#pragma unroll
                for (int c = 0; c < CC; ++c) {
                    float xr = xrp[c*4 + tt], xi = xip[c*4 + tt];
                    float wr = wk_r[(f*BB + b)*CC + c];
                    float wi = wk_i[(f*BB + b)*CC + c];
                    kr += xr*wr - xi*wi;
                    ki += xi*wr + xr*wi;
                }
                acc += bq[tt] * sqrtf(kr*kr + ki*ki + EPSF);
            }
            part[b] = acc;
        }
    }

    __shared__ float red[4][BB];
    int lane = threadIdx.x & 63, wv = threadIdx.x >> 6;
#pragma unroll
    for (int b = 0; b < BB; ++b) {
        float v = part[b];
#pragma unroll
        for (int m = 32; m >= 1; m >>= 1) v += __shfl_xor(v, m);
        if (lane == 0) red[wv][b] = v;
    }
    __syncthreads();
    if (threadIdx.x < BB) {
        float v = red[0][threadIdx.x] + red[1][threadIdx.x]
                + red[2][threadIdx.x] + red[3][threadIdx.x];
        int bin = (blockIdx.x * 2 + blockIdx.y) & 15;
        atomicAdd(&s_buf[bin*64 + n*BB + threadIdx.x], v);
    }
}

// ---------------- kernel 2: softmax over B per n (sums 16 bins) ----------------
__global__ void k_softmax(const float* __restrict__ s_buf, float* __restrict__ w_buf)
{
    int tid = threadIdx.x;
    if (tid < NN*BB) {
        float v = 0.f;
#pragma unroll
        for (int j = 0; j < 16; ++j) v += s_buf[j*64 + tid];
        v *= (1.0f / TT);
        float mx = v;
#pragma unroll
        for (int m = 4; m >= 1; m >>= 1) mx = fmaxf(mx, __shfl_xor(mx, m));
        float e = expf(v - mx);
        float sm = e;
#pragma unroll
        for (int m = 4; m >= 1; m >>= 1) sm += __shfl_xor(sm, m);
        w_buf[tid] = e / sm;
    }
}

// ---------------- kernel 2b: repack proj_w into padded stride-260 ----------------
__global__ void k_prep(const float* __restrict__ proj_w, float* __restrict__ proj_pad)
{
    int i = blockIdx.x * 256 + threadIdx.x;
    if (i < MM * 260) {
        int m = i / 260, f = i % 260;
        proj_pad[i] = (f < FF) ? proj_w[m*FF + f] : 0.f;
    }
}

// ---------------- kernel 3a: v[n,f,t] = sum_b w_b * |beam_v| (streaming) ----------------
// grid (NN*FF, 2), block 256; float4 over t.
__global__ __launch_bounds__(256) void k_vcompute(
    const float* __restrict__ xr_g, const float* __restrict__ xi_g,
    const float* __restrict__ wv_r, const float* __restrict__ wv_i,
    const float* __restrict__ w_buf, float* __restrict__ vbuf)
{
    int nf = blockIdx.x;
    int n = nf / FF, f = nf % FF;
    int t4 = blockIdx.y * 256 + threadIdx.x;
    if (t4 >= T4N) return;

    const float* xr_base = xr_g + ((size_t)(n*CC)*FF + f) * TT + t4*4;
    const float* xi_base = xi_g + ((size_t)(n*CC)*FF + f) * TT + t4*4;
    float4 xr4[CC], xi4[CC];
#pragma unroll
    for (int c = 0; c < CC; ++c) {
        xr4[c] = *reinterpret_cast<const float4*>(xr_base + (size_t)c*FF*TT);
        xi4[c] = *reinterpret_cast<const float4*>(xi_base + (size_t)c*FF*TT);
    }
    const float* xrp = (const float*)xr4;
    const float* xip = (const float*)xi4;

    float vout[4] = {0.f, 0.f, 0.f, 0.f};
#pragma unroll
    for (int b = 0; b < BB; ++b) {
        float wn = w_buf[n*BB + b];                      // n uniform -> scalar
        const float4 wr4 = *reinterpret_cast<const float4*>(&wv_r[(f*BB + b)*CC]);
        const float4 wi4 = *reinterpret_cast<const float4*>(&wv_i[(f*BB + b)*CC]);
        const float* wrp = (const float*)&wr4;
        const float* wip = (const float*)&wi4;
#pragma unroll
        for (int tt = 0; tt < 4; ++tt) {
            float vr = 0.f, vi = 0.f;
#pragma unroll
            for (int c = 0; c < CC; ++c) {
                float xr = xrp[c*4 + tt], xi = xip[c*4 + tt];
                vr += xr*wrp[c] - xi*wip[c];
                vi += xi*wrp[c] + xr*wip[c];
            }
            vout[tt] += wn * sqrtf(vr*vr + vi*vi + EPSF);
        }
    }
    float4 o; o.x = vout[0]; o.y = vout[1]; o.z = vout[2]; o.w = vout[3];
    *reinterpret_cast<float4*>(&vbuf[((size_t)(n*FF + f))*TT + t4*4]) = o;
}

// ---------------- kernel 3b: project, relu, log, BN partials ----------------
// grid (NN, 63), block 256. LDS tile 32t x 261f; 10 m-accumulators/thread.
__global__ __launch_bounds__(256) void k_proj(
    const float* __restrict__ vbuf, const float* __restrict__ proj_pad,
    float* __restrict__ out, double* __restrict__ bn_sum, double* __restrict__ bn_sumsq)
{
    __shared__ float v_lds[32 * VSTR];
    int n = blockIdx.x, chunk = blockIdx.y;
    int t0 = chunk * 32;
    int tl = threadIdx.x & 31, fg = threadIdx.x >> 5;
    int t = t0 + tl;
    bool tvalid = (t < TT);

#pragma unroll
    for (int k = 0; k < 33; ++k) {
        int f = fg + 8*k;
        if (f < 261) {
            float v = 0.f;
            if (f < FF && tvalid) v = vbuf[((size_t)(n*FF + f))*TT + t];
            v_lds[tl*VSTR + f] = v;
        }
    }
    __syncthreads();

    float acc[10];
#pragma unroll
    for (int j = 0; j < 10; ++j) acc[j] = 0.f;
    const float* pp = proj_pad + fg * 10 * 260;
#pragma unroll 4
    for (int f4 = 0; f4 < 260; f4 += 4) {
        float v0 = v_lds[tl*VSTR + f4 + 0];
        float v1 = v_lds[tl*VSTR + f4 + 1];
        float v2 = v_lds[tl*VSTR + f4 + 2];
        float v3 = v_lds[tl*VSTR + f4 + 3];
#pragma unroll
        for (int j = 0; j < 10; ++j) {
            float4 p = *reinterpret_cast<const float4*>(&pp[j*260 + f4]);
            acc[j] += v0*p.x + v1*p.y + v2*p.z + v3*p.w;
        }
    }

    int bin = chunk & 7;
#pragma unroll
    for (int j = 0; j < 10; ++j) {
        int m = fg*10 + j;
        float r = logf(fmaxf(acc[j], 0.f) + EPSF);
        float s1 = tvalid ? r : 0.f;
        float s2 = tvalid ? r*r : 0.f;
#pragma unroll
        for (int msk = 16; msk >= 1; msk >>= 1) {
            s1 += __shfl_xor(s1, msk);
            s2 += __shfl_xor(s2, msk);
        }
        if (tvalid) out[((size_t)n*TT + t)*MM + m] = r;
        if (tl == 0) {
            atomicAdd(&bn_sum[bin*MM + m], (double)s1);
            atomicAdd(&bn_sumsq[bin*MM + m], (double)s2);
        }
    }
}

// ---------------- kernel 4a: BN finalize (sums 8 bins) ----------------
__global__ void k_bnprep(const double* __restrict__ bn_sum, const double* __restrict__ bn_sumsq,
                         const float* __restrict__ gamma, const float* __restrict__ beta,
                         float* __restrict__ scale, float* __restrict__ shift)
{
    int m = threadIdx.x;
    if (m < MM) {
        double s = 0.0, q = 0.0;
#pragma unroll
        for (int j = 0; j < 8; ++j) { s += bn_sum[j*MM + m]; q += bn_sumsq[j*MM + m]; }
        double inv = 1.0 / (double)(NN * TT);
        double mu = s * inv;
        double var = q * inv - mu * mu;
        float sc = gamma[m] * rsqrtf((float)var + EPSF);
        scale[m] = sc;
        shift[m] = beta[m] - (float)mu * sc;
    }
}

// ---------------- kernel 4b: BN apply in-place (float4) ----------------
__global__ __launch_bounds__(256) void k_bnapply(float* __restrict__ out,
                                                 const float* __restrict__ scale,
                                                 const float* __restrict__ shift)
{
    int i4 = blockIdx.x * 256 + threadIdx.x;
    if (i4 < NN*TT*MM/4) {
        float4 v = *reinterpret_cast<const float4*>(&out[i4*4]);
        int m = (i4*4) % MM;
        v.x = v.x*scale[m+0] + shift[m+0];
        v.y = v.y*scale[m+1] + shift[m+1];
        v.z = v.z*scale[m+2] + shift[m+2];
        v.w = v.w*scale[m+3] + shift[m+3];
        *reinterpret_cast<float4*>(&out[i4*4]) = v;
    }
}

extern "C" void kernel_launch(void* const* d_in, const int* in_sizes, int n_in,
                              void* d_out, int out_size, void* d_ws, size_t ws_size,
                              hipStream_t stream)
{
    const float* x_real   = (const float*)d_in[0];
    const float* x_imag   = (const float*)d_in[1];
    const float* wq_r     = (const float*)d_in[2];
    const float* wq_i     = (const float*)d_in[3];
    const float* wk_r     = (const float*)d_in[4];
    const float* wk_i     = (const float*)d_in[5];
    const float* wv_r     = (const float*)d_in[6];
    const float* wv_i     = (const float*)d_in[7];
    const float* proj_w   = (const float*)d_in[8];
    const float* bn_gamma = (const float*)d_in[9];
    const float* bn_beta  = (const float*)d_in[10];
    float* out = (float*)d_out;

    char* ws = (char*)d_ws;
    float*  s_buf    = (float*)(ws + 0);        // 16 bins x 64 = 1024 floats (4096 B)
    float*  w_buf    = (float*)(ws + 4096);     // 64 floats
    float*  scale    = (float*)(ws + 4352);     // 80 floats
    float*  shift    = (float*)(ws + 4672);     // 80 floats
    double* bn_sum   = (double*)(ws + 8192);    // 8 bins x 80 doubles (5120 B)
    double* bn_sumsq = (double*)(ws + 13312);   // 8 bins x 80 doubles (5120 B)
    float*  proj_pad = (float*)(ws + 18432);    // 80*260 floats (83200 B)
    float*  vbuf     = (float*)(ws + 101632);   // 8*257*2000 floats (16448000 B)

    hipMemsetAsync(d_ws, 0, 18432, stream);     // zero s_buf + bn bins

    k_prep<<<(MM*260 + 255)/256, 256, 0, stream>>>(proj_w, proj_pad);

    dim3 g1(NN*FF, 2);
    k_beam_s<<<g1, 256, 0, stream>>>(x_real, x_imag, wq_r, wq_i, wk_r, wk_i, s_buf);

    k_softmax<<<1, 64, 0, stream>>>(s_buf, w_buf);

    k_vcompute<<<g1, 256, 0, stream>>>(x_real, x_imag, wv_r, wv_i, w_buf, vbuf);

    dim3 g3(NN, 63);
    k_proj<<<g3, 256, 0, stream>>>(vbuf, proj_pad, out, bn_sum, bn_sumsq);

    k_bnprep<<<1, 128, 0, stream>>>(bn_sum, bn_sumsq, bn_gamma, bn_beta, scale, shift);

    k_bnapply<<<(NN*TT*MM/4 + 255)/256, 256, 0, stream>>>(out, scale, shift);
}

// Round 3
// 149.433 us; speedup vs baseline: 1.9508x; 1.1219x over previous
//
#include <hip/hip_runtime.h>
#include <math.h>

#define NN 8
#define CC 4
#define FF 257
#define TT 2000
#define BB 8
#define MM 80
#define EPSF 1e-5f
#define VSTR 261   // odd stride -> conflict-free LDS (261 % 32 = 5, coprime with 32)
#define T4N 500    // TT/4

__device__ __forceinline__ float fsqrt_fast(float x) { return __builtin_amdgcn_sqrtf(x); }
__device__ __forceinline__ float flog_fast(float x)  { return __builtin_amdgcn_logf(x) * 0.69314718055994531f; }

// ---------------- kernel 1: beamform q,k and reduce s partials ----------------
// grid (NN*FF, 2), block 256. Each thread: 4 consecutive t via float4.
__global__ __launch_bounds__(256) void k_beam_s(
    const float* __restrict__ xr_g, const float* __restrict__ xi_g,
    const float* __restrict__ wq_r, const float* __restrict__ wq_i,
    const float* __restrict__ wk_r, const float* __restrict__ wk_i,
    float* __restrict__ s_buf)
{
    int nf = blockIdx.x;
    int n = nf / FF, f = nf % FF;
    int t4 = blockIdx.y * 256 + threadIdx.x;

    float part[BB];
#pragma unroll
    for (int b = 0; b < BB; ++b) part[b] = 0.f;

    if (t4 < T4N) {
        const float* xr_base = xr_g + ((size_t)(n*CC)*FF + f) * TT + t4*4;
        const float* xi_base = xi_g + ((size_t)(n*CC)*FF + f) * TT + t4*4;
        float4 xr4[CC], xi4[CC];
#pragma unroll
        for (int c = 0; c < CC; ++c) {
            xr4[c] = *reinterpret_cast<const float4*>(xr_base + (size_t)c*FF*TT);
            xi4[c] = *reinterpret_cast<const float4*>(xi_base + (size_t)c*FF*TT);
        }
        const float* xrp = (const float*)xr4;
        const float* xip = (const float*)xi4;

        float qq[4];
#pragma unroll
        for (int tt = 0; tt < 4; ++tt) {
            float qr = 0.f, qi = 0.f;
#pragma unroll
            for (int c = 0; c < CC; ++c) {
                float xr = xrp[c*4 + tt], xi = xip[c*4 + tt];
                float wr = wq_r[f*CC + c], wi = wq_i[f*CC + c];  // f uniform -> scalar
                qr += xr*wr - xi*wi;
                qi += xi*wr + xr*wi;
            }
            qq[tt] = qr*qr + qi*qi + EPSF;
        }
#pragma unroll
        for (int b = 0; b < BB; ++b) {
            float acc = 0.f;
#pragma unroll
            for (int tt = 0; tt < 4; ++tt) {
                float kr = 0.f, ki = 0.f;
#pragma unroll
                for (int c = 0; c < CC; ++c) {
                    float xr = xrp[c*4 + tt], xi = xip[c*4 + tt];
                    float wr = wk_r[(f*BB + b)*CC + c];
                    float wi = wk_i[(f*BB + b)*CC + c];
                    kr += xr*wr - xi*wi;
                    ki += xi*wr + xr*wi;
                }
                float kk = kr*kr + ki*ki + EPSF;
                // bq*bk = sqrt(qq)*sqrt(kk) = sqrt(qq*kk)  (1 sqrt instead of 2)
                acc += fsqrt_fast(qq[tt] * kk);
            }
            part[b] = acc;
        }
    }

    __shared__ float red[4][BB];
    int lane = threadIdx.x & 63, wv = threadIdx.x >> 6;
#pragma unroll
    for (int b = 0; b < BB; ++b) {
        float v = part[b];
#pragma unroll
        for (int m = 32; m >= 1; m >>= 1) v += __shfl_xor(v, m);
        if (lane == 0) red[wv][b] = v;
    }
    __syncthreads();
    if (threadIdx.x < BB) {
        float v = red[0][threadIdx.x] + red[1][threadIdx.x]
                + red[2][threadIdx.x] + red[3][threadIdx.x];
        int bin = (blockIdx.x * 2 + blockIdx.y) & 15;
        atomicAdd(&s_buf[bin*64 + n*BB + threadIdx.x], v);
    }
}

// ---------------- kernel 2: softmax over B per n (sums 16 bins) ----------------
__global__ void k_softmax(const float* __restrict__ s_buf, float* __restrict__ w_buf)
{
    int tid = threadIdx.x;
    if (tid < NN*BB) {
        float v = 0.f;
#pragma unroll
        for (int j = 0; j < 16; ++j) v += s_buf[j*64 + tid];
        v *= (1.0f / TT);
        float mx = v;
#pragma unroll
        for (int m = 4; m >= 1; m >>= 1) mx = fmaxf(mx, __shfl_xor(mx, m));
        float e = expf(v - mx);
        float sm = e;
#pragma unroll
        for (int m = 4; m >= 1; m >>= 1) sm += __shfl_xor(sm, m);
        w_buf[tid] = e / sm;
    }
}

// ---------------- kernel 2b: repack proj_w into padded stride-260 ----------------
__global__ void k_prep(const float* __restrict__ proj_w, float* __restrict__ proj_pad)
{
    int i = blockIdx.x * 256 + threadIdx.x;
    if (i < MM * 260) {
        int m = i / 260, f = i % 260;
        proj_pad[i] = (f < FF) ? proj_w[m*FF + f] : 0.f;
    }
}

// ---------------- kernel 3a: v[n,f,t] = sum_b w_b * |beam_v| (streaming) ----------------
// grid (NN*FF, 2), block 256; float4 over t.
__global__ __launch_bounds__(256) void k_vcompute(
    const float* __restrict__ xr_g, const float* __restrict__ xi_g,
    const float* __restrict__ wv_r, const float* __restrict__ wv_i,
    const float* __restrict__ w_buf, float* __restrict__ vbuf)
{
    int nf = blockIdx.x;
    int n = nf / FF, f = nf % FF;
    int t4 = blockIdx.y * 256 + threadIdx.x;
    if (t4 >= T4N) return;

    const float* xr_base = xr_g + ((size_t)(n*CC)*FF + f) * TT + t4*4;
    const float* xi_base = xi_g + ((size_t)(n*CC)*FF + f) * TT + t4*4;
    float4 xr4[CC], xi4[CC];
#pragma unroll
    for (int c = 0; c < CC; ++c) {
        xr4[c] = *reinterpret_cast<const float4*>(xr_base + (size_t)c*FF*TT);
        xi4[c] = *reinterpret_cast<const float4*>(xi_base + (size_t)c*FF*TT);
    }
    const float* xrp = (const float*)xr4;
    const float* xip = (const float*)xi4;

    float vout[4] = {0.f, 0.f, 0.f, 0.f};
#pragma unroll
    for (int b = 0; b < BB; ++b) {
        float wn = w_buf[n*BB + b];                      // n uniform -> scalar
        const float4 wr4 = *reinterpret_cast<const float4*>(&wv_r[(f*BB + b)*CC]);
        const float4 wi4 = *reinterpret_cast<const float4*>(&wv_i[(f*BB + b)*CC]);
        const float* wrp = (const float*)&wr4;
        const float* wip = (const float*)&wi4;
#pragma unroll
        for (int tt = 0; tt < 4; ++tt) {
            float vr = 0.f, vi = 0.f;
#pragma unroll
            for (int c = 0; c < CC; ++c) {
                float xr = xrp[c*4 + tt], xi = xip[c*4 + tt];
                vr += xr*wrp[c] - xi*wip[c];
                vi += xi*wrp[c] + xr*wip[c];
            }
            vout[tt] += wn * fsqrt_fast(vr*vr + vi*vi + EPSF);
        }
    }
    float4 o; o.x = vout[0]; o.y = vout[1]; o.z = vout[2]; o.w = vout[3];
    *reinterpret_cast<float4*>(&vbuf[((size_t)(n*FF + f))*TT + t4*4]) = o;
}

// ---------------- kernel 3b: project, relu, log, BN partials ----------------
// grid (NN, 63), block 256. LDS tile 32t x 261f; 10 m-accumulators/thread.
__global__ __launch_bounds__(256) void k_proj(
    const float* __restrict__ vbuf, const float* __restrict__ proj_pad,
    float* __restrict__ out, double* __restrict__ bn_sum, double* __restrict__ bn_sumsq)
{
    __shared__ float v_lds[32 * VSTR];
    int n = blockIdx.x, chunk = blockIdx.y;
    int t0 = chunk * 32;
    int tl = threadIdx.x & 31, fg = threadIdx.x >> 5;
    int t = t0 + tl;
    bool tvalid = (t < TT);

#pragma unroll
    for (int k = 0; k < 33; ++k) {
        int f = fg + 8*k;
        if (f < 261) {
            float v = 0.f;
            if (f < FF && tvalid) v = vbuf[((size_t)(n*FF + f))*TT + t];
            v_lds[tl*VSTR + f] = v;
        }
    }
    __syncthreads();

    float acc[10];
#pragma unroll
    for (int j = 0; j < 10; ++j) acc[j] = 0.f;
    const float* pp = proj_pad + fg * 10 * 260;
#pragma unroll 4
    for (int f4 = 0; f4 < 260; f4 += 4) {
        float v0 = v_lds[tl*VSTR + f4 + 0];
        float v1 = v_lds[tl*VSTR + f4 + 1];
        float v2 = v_lds[tl*VSTR + f4 + 2];
        float v3 = v_lds[tl*VSTR + f4 + 3];
#pragma unroll
        for (int j = 0; j < 10; ++j) {
            float4 p = *reinterpret_cast<const float4*>(&pp[j*260 + f4]);
            acc[j] += v0*p.x + v1*p.y + v2*p.z + v3*p.w;
        }
    }

    int bin = chunk & 7;
#pragma unroll
    for (int j = 0; j < 10; ++j) {
        int m = fg*10 + j;
        float r = flog_fast(fmaxf(acc[j], 0.f) + EPSF);
        float s1 = tvalid ? r : 0.f;
        float s2 = tvalid ? r*r : 0.f;
#pragma unroll
        for (int msk = 16; msk >= 1; msk >>= 1) {
            s1 += __shfl_xor(s1, msk);
            s2 += __shfl_xor(s2, msk);
        }
        if (tvalid) out[((size_t)n*TT + t)*MM + m] = r;
        if (tl == 0) {
            atomicAdd(&bn_sum[bin*MM + m], (double)s1);
            atomicAdd(&bn_sumsq[bin*MM + m], (double)s2);
        }
    }
}

// ---------------- kernel 4a: BN finalize (sums 8 bins) ----------------
__global__ void k_bnprep(const double* __restrict__ bn_sum, const double* __restrict__ bn_sumsq,
                         const float* __restrict__ gamma, const float* __restrict__ beta,
                         float* __restrict__ scale, float* __restrict__ shift)
{
    int m = threadIdx.x;
    if (m < MM) {
        double s = 0.0, q = 0.0;
#pragma unroll
        for (int j = 0; j < 8; ++j) { s += bn_sum[j*MM + m]; q += bn_sumsq[j*MM + m]; }
        double inv = 1.0 / (double)(NN * TT);
        double mu = s * inv;
        double var = q * inv - mu * mu;
        float sc = gamma[m] * rsqrtf((float)var + EPSF);
        scale[m] = sc;
        shift[m] = beta[m] - (float)mu * sc;
    }
}

// ---------------- kernel 4b: BN apply in-place (float4) ----------------
__global__ __launch_bounds__(256) void k_bnapply(float* __restrict__ out,
                                                 const float* __restrict__ scale,
                                                 const float* __restrict__ shift)
{
    int i4 = blockIdx.x * 256 + threadIdx.x;
    if (i4 < NN*TT*MM/4) {
        float4 v = *reinterpret_cast<const float4*>(&out[i4*4]);
        int m = (i4*4) % MM;
        v.x = v.x*scale[m+0] + shift[m+0];
        v.y = v.y*scale[m+1] + shift[m+1];
        v.z = v.z*scale[m+2] + shift[m+2];
        v.w = v.w*scale[m+3] + shift[m+3];
        *reinterpret_cast<float4*>(&out[i4*4]) = v;
    }
}

extern "C" void kernel_launch(void* const* d_in, const int* in_sizes, int n_in,
                              void* d_out, int out_size, void* d_ws, size_t ws_size,
                              hipStream_t stream)
{
    const float* x_real   = (const float*)d_in[0];
    const float* x_imag   = (const float*)d_in[1];
    const float* wq_r     = (const float*)d_in[2];
    const float* wq_i     = (const float*)d_in[3];
    const float* wk_r     = (const float*)d_in[4];
    const float* wk_i     = (const float*)d_in[5];
    const float* wv_r     = (const float*)d_in[6];
    const float* wv_i     = (const float*)d_in[7];
    const float* proj_w   = (const float*)d_in[8];
    const float* bn_gamma = (const float*)d_in[9];
    const float* bn_beta  = (const float*)d_in[10];
    float* out = (float*)d_out;

    char* ws = (char*)d_ws;
    float*  s_buf    = (float*)(ws + 0);        // 16 bins x 64 = 1024 floats (4096 B)
    float*  w_buf    = (float*)(ws + 4096);     // 64 floats
    float*  scale    = (float*)(ws + 4352);     // 80 floats
    float*  shift    = (float*)(ws + 4672);     // 80 floats
    double* bn_sum   = (double*)(ws + 8192);    // 8 bins x 80 doubles (5120 B)
    double* bn_sumsq = (double*)(ws + 13312);   // 8 bins x 80 doubles (5120 B)
    float*  proj_pad = (float*)(ws + 18432);    // 80*260 floats (83200 B)
    float*  vbuf     = (float*)(ws + 101632);   // 8*257*2000 floats (16448000 B)

    hipMemsetAsync(d_ws, 0, 18432, stream);     // zero s_buf + bn bins

    k_prep<<<(MM*260 + 255)/256, 256, 0, stream>>>(proj_w, proj_pad);

    dim3 g1(NN*FF, 2);
    k_beam_s<<<g1, 256, 0, stream>>>(x_real, x_imag, wq_r, wq_i, wk_r, wk_i, s_buf);

    k_softmax<<<1, 64, 0, stream>>>(s_buf, w_buf);

    k_vcompute<<<g1, 256, 0, stream>>>(x_real, x_imag, wv_r, wv_i, w_buf, vbuf);

    dim3 g3(NN, 63);
    k_proj<<<g3, 256, 0, stream>>>(vbuf, proj_pad, out, bn_sum, bn_sumsq);

    k_bnprep<<<1, 128, 0, stream>>>(bn_sum, bn_sumsq, bn_gamma, bn_beta, scale, shift);

    k_bnapply<<<(NN*TT*MM/4 + 255)/256, 256, 0, stream>>>(out, scale, shift);
}

// Round 4
// 129.522 us; speedup vs baseline: 2.2507x; 1.1537x over previous
//
#include <hip/hip_runtime.h>
#include <math.h>

#define NN 8
#define CC 4
#define FF 257
#define TT 2000
#define BB 8
#define MM 80
#define EPSF 1e-5f
#define VSTR 261   // odd stride -> conflict-free LDS (261 % 32 = 5, coprime with 32)
#define T4N 500    // TT/4

__device__ __forceinline__ float fsqrt_fast(float x) { return __builtin_amdgcn_sqrtf(x); }
__device__ __forceinline__ float flog_fast(float x)  { return __builtin_amdgcn_logf(x) * 0.69314718055994531f; }

// ---------------- kernel 1: beamform q,k and reduce s partials ----------------
// grid (NN*FF, 2), block 256. Each thread: 4 consecutive t via float4.
__global__ __launch_bounds__(256) void k_beam_s(
    const float* __restrict__ xr_g, const float* __restrict__ xi_g,
    const float* __restrict__ wq_r, const float* __restrict__ wq_i,
    const float* __restrict__ wk_r, const float* __restrict__ wk_i,
    float* __restrict__ s_buf)
{
    int nf = blockIdx.x;
    int n = nf / FF, f = nf % FF;
    int t4 = blockIdx.y * 256 + threadIdx.x;

    float part[BB];
#pragma unroll
    for (int b = 0; b < BB; ++b) part[b] = 0.f;

    if (t4 < T4N) {
        const float* xr_base = xr_g + ((size_t)(n*CC)*FF + f) * TT + t4*4;
        const float* xi_base = xi_g + ((size_t)(n*CC)*FF + f) * TT + t4*4;
        float4 xr4[CC], xi4[CC];
#pragma unroll
        for (int c = 0; c < CC; ++c) {
            xr4[c] = *reinterpret_cast<const float4*>(xr_base + (size_t)c*FF*TT);
            xi4[c] = *reinterpret_cast<const float4*>(xi_base + (size_t)c*FF*TT);
        }
        const float* xrp = (const float*)xr4;
        const float* xip = (const float*)xi4;

        float qq[4];
#pragma unroll
        for (int tt = 0; tt < 4; ++tt) {
            float qr = 0.f, qi = 0.f;
#pragma unroll
            for (int c = 0; c < CC; ++c) {
                float xr = xrp[c*4 + tt], xi = xip[c*4 + tt];
                float wr = wq_r[f*CC + c], wi = wq_i[f*CC + c];  // f uniform -> scalar
                qr += xr*wr - xi*wi;
                qi += xi*wr + xr*wi;
            }
            qq[tt] = qr*qr + qi*qi + EPSF;
        }
#pragma unroll
        for (int b = 0; b < BB; ++b) {
            float acc = 0.f;
#pragma unroll
            for (int tt = 0; tt < 4; ++tt) {
                float kr = 0.f, ki = 0.f;
#pragma unroll
                for (int c = 0; c < CC; ++c) {
                    float xr = xrp[c*4 + tt], xi = xip[c*4 + tt];
                    float wr = wk_r[(f*BB + b)*CC + c];
                    float wi = wk_i[(f*BB + b)*CC + c];
                    kr += xr*wr - xi*wi;
                    ki += xi*wr + xr*wi;
                }
                float kk = kr*kr + ki*ki + EPSF;
                acc += fsqrt_fast(qq[tt] * kk);   // sqrt(qq)*sqrt(kk) fused
            }
            part[b] = acc;
        }
    }

    __shared__ float red[4][BB];
    int lane = threadIdx.x & 63, wv = threadIdx.x >> 6;
#pragma unroll
    for (int b = 0; b < BB; ++b) {
        float v = part[b];
#pragma unroll
        for (int m = 32; m >= 1; m >>= 1) v += __shfl_xor(v, m);
        if (lane == 0) red[wv][b] = v;
    }
    __syncthreads();
    if (threadIdx.x < BB) {
        float v = red[0][threadIdx.x] + red[1][threadIdx.x]
                + red[2][threadIdx.x] + red[3][threadIdx.x];
        int bin = (blockIdx.x * 2 + blockIdx.y) & 15;
        atomicAdd(&s_buf[bin*64 + n*BB + threadIdx.x], v);
    }
}

// ---------------- kernel 2: softmax over B per n (sums 16 bins) ----------------
__global__ void k_softmax(const float* __restrict__ s_buf, float* __restrict__ w_buf)
{
    int tid = threadIdx.x;
    if (tid < NN*BB) {
        float v = 0.f;
#pragma unroll
        for (int j = 0; j < 16; ++j) v += s_buf[j*64 + tid];
        v *= (1.0f / TT);
        float mx = v;
#pragma unroll
        for (int m = 4; m >= 1; m >>= 1) mx = fmaxf(mx, __shfl_xor(mx, m));
        float e = expf(v - mx);
        float sm = e;
#pragma unroll
        for (int m = 4; m >= 1; m >>= 1) sm += __shfl_xor(sm, m);
        w_buf[tid] = e / sm;
    }
}

// ---------------- kernel 2b: repack proj_w into padded stride-260 ----------------
__global__ void k_prep(const float* __restrict__ proj_w, float* __restrict__ proj_pad)
{
    int i = blockIdx.x * 256 + threadIdx.x;
    if (i < MM * 260) {
        int m = i / 260, f = i % 260;
        proj_pad[i] = (f < FF) ? proj_w[m*FF + f] : 0.f;
    }
}

// ---------------- kernel 3 (FUSED): v from x -> LDS, project, relu, log, BN partials ----
// grid (NN, 125), block 256. t-tile = 16 (125*16 = 2000, no tail).
// Fill stage:  thread = (t4s = tid&3, fbase = tid>>2): 4 lanes cover one f's 16 t -> 64B sectors.
// Proj stage:  thread = (tl = tid&15, fg = tid>>4): 5 m per thread over 260 f from LDS.
__global__ __launch_bounds__(256) void k_vproj(
    const float* __restrict__ xr_g, const float* __restrict__ xi_g,
    const float* __restrict__ wv_r, const float* __restrict__ wv_i,
    const float* __restrict__ w_buf, const float* __restrict__ proj_pad,
    float* __restrict__ out, double* __restrict__ bn_sum, double* __restrict__ bn_sumsq)
{
    __shared__ float v_lds[16 * VSTR];
    int n = blockIdx.x, chunk = blockIdx.y;
    int t0 = chunk * 16;
    int tid = threadIdx.x;

    float wn[BB];
#pragma unroll
    for (int b = 0; b < BB; ++b) wn[b] = w_buf[n*BB + b];   // n uniform -> scalar

    // zero the pad columns f = 257..260 (protect against stale LDS * 0 = NaN issues)
    if (tid < 64) {
        int t = tid >> 2, f = FF + (tid & 3);
        v_lds[t*VSTR + f] = 0.f;
    }

    int t4s = tid & 3;      // which float4 of the 16-t tile
    int fbase = tid >> 2;   // 0..63

#pragma unroll 1
    for (int k = 0; k < 5; ++k) {
        int f = fbase + 64*k;
        if (f < FF) {
            float4 xr4[CC], xi4[CC];
#pragma unroll
            for (int c = 0; c < CC; ++c) {
                size_t base = ((size_t)(n*CC + c)*FF + f)*TT + t0 + t4s*4;
                xr4[c] = *reinterpret_cast<const float4*>(xr_g + base);
                xi4[c] = *reinterpret_cast<const float4*>(xi_g + base);
            }
            const float* xrp = (const float*)xr4;
            const float* xip = (const float*)xi4;

            float vo[4] = {0.f, 0.f, 0.f, 0.f};
#pragma unroll
            for (int b = 0; b < BB; ++b) {
                const float4 wr4 = *reinterpret_cast<const float4*>(&wv_r[(f*BB + b)*CC]);
                const float4 wi4 = *reinterpret_cast<const float4*>(&wv_i[(f*BB + b)*CC]);
                const float* wrp = (const float*)&wr4;
                const float* wip = (const float*)&wi4;
#pragma unroll
                for (int tt = 0; tt < 4; ++tt) {
                    float vr = 0.f, vi = 0.f;
#pragma unroll
                    for (int c = 0; c < CC; ++c) {
                        float xr = xrp[c*4 + tt], xi = xip[c*4 + tt];
                        vr += xr*wrp[c] - xi*wip[c];
                        vi += xi*wrp[c] + xr*wip[c];
                    }
                    vo[tt] += wn[b] * fsqrt_fast(vr*vr + vi*vi + EPSF);
                }
            }
#pragma unroll
            for (int tt = 0; tt < 4; ++tt)
                v_lds[(t4s*4 + tt)*VSTR + f] = vo[tt];
        }
    }
    __syncthreads();

    // ---- proj stage ----
    int tl = tid & 15, fg = tid >> 4;
    float acc[5];
#pragma unroll
    for (int j = 0; j < 5; ++j) acc[j] = 0.f;
    const float* pp = proj_pad + fg * 5 * 260;
#pragma unroll 4
    for (int f4 = 0; f4 < 260; f4 += 4) {
        float v0 = v_lds[tl*VSTR + f4 + 0];
        float v1 = v_lds[tl*VSTR + f4 + 1];
        float v2 = v_lds[tl*VSTR + f4 + 2];
        float v3 = v_lds[tl*VSTR + f4 + 3];
#pragma unroll
        for (int j = 0; j < 5; ++j) {
            float4 p = *reinterpret_cast<const float4*>(&pp[j*260 + f4]);
            acc[j] += v0*p.x + v1*p.y + v2*p.z + v3*p.w;
        }
    }

    int t = t0 + tl;
    int bin = chunk & 15;
#pragma unroll
    for (int j = 0; j < 5; ++j) {
        int m = fg*5 + j;
        float r = flog_fast(fmaxf(acc[j], 0.f) + EPSF);
        float s1 = r, s2 = r*r;
#pragma unroll
        for (int msk = 8; msk >= 1; msk >>= 1) {
            s1 += __shfl_xor(s1, msk);
            s2 += __shfl_xor(s2, msk);
        }
        out[((size_t)n*TT + t)*MM + m] = r;
        if (tl == 0) {
            atomicAdd(&bn_sum[bin*MM + m], (double)s1);
            atomicAdd(&bn_sumsq[bin*MM + m], (double)s2);
        }
    }
}

// ---------------- kernel 4a: BN finalize (sums 16 bins) ----------------
__global__ void k_bnprep(const double* __restrict__ bn_sum, const double* __restrict__ bn_sumsq,
                         const float* __restrict__ gamma, const float* __restrict__ beta,
                         float* __restrict__ scale, float* __restrict__ shift)
{
    int m = threadIdx.x;
    if (m < MM) {
        double s = 0.0, q = 0.0;
#pragma unroll
        for (int j = 0; j < 16; ++j) { s += bn_sum[j*MM + m]; q += bn_sumsq[j*MM + m]; }
        double inv = 1.0 / (double)(NN * TT);
        double mu = s * inv;
        double var = q * inv - mu * mu;
        float sc = gamma[m] * rsqrtf((float)var + EPSF);
        scale[m] = sc;
        shift[m] = beta[m] - (float)mu * sc;
    }
}

// ---------------- kernel 4b: BN apply in-place (float4) ----------------
__global__ __launch_bounds__(256) void k_bnapply(float* __restrict__ out,
                                                 const float* __restrict__ scale,
                                                 const float* __restrict__ shift)
{
    int i4 = blockIdx.x * 256 + threadIdx.x;
    if (i4 < NN*TT*MM/4) {
        float4 v = *reinterpret_cast<const float4*>(&out[i4*4]);
        int m = (i4*4) % MM;
        v.x = v.x*scale[m+0] + shift[m+0];
        v.y = v.y*scale[m+1] + shift[m+1];
        v.z = v.z*scale[m+2] + shift[m+2];
        v.w = v.w*scale[m+3] + shift[m+3];
        *reinterpret_cast<float4*>(&out[i4*4]) = v;
    }
}

extern "C" void kernel_launch(void* const* d_in, const int* in_sizes, int n_in,
                              void* d_out, int out_size, void* d_ws, size_t ws_size,
                              hipStream_t stream)
{
    const float* x_real   = (const float*)d_in[0];
    const float* x_imag   = (const float*)d_in[1];
    const float* wq_r     = (const float*)d_in[2];
    const float* wq_i     = (const float*)d_in[3];
    const float* wk_r     = (const float*)d_in[4];
    const float* wk_i     = (const float*)d_in[5];
    const float* wv_r     = (const float*)d_in[6];
    const float* wv_i     = (const float*)d_in[7];
    const float* proj_w   = (const float*)d_in[8];
    const float* bn_gamma = (const float*)d_in[9];
    const float* bn_beta  = (const float*)d_in[10];
    float* out = (float*)d_out;

    char* ws = (char*)d_ws;
    float*  s_buf    = (float*)(ws + 0);        // 16 bins x 64 floats (4096 B)
    float*  w_buf    = (float*)(ws + 4096);     // 64 floats
    float*  scale    = (float*)(ws + 4352);     // 80 floats
    float*  shift    = (float*)(ws + 4672);     // 80 floats
    double* bn_sum   = (double*)(ws + 8192);    // 16 bins x 80 doubles (10240 B)
    double* bn_sumsq = (double*)(ws + 18432);   // 16 bins x 80 doubles (10240 B)
    float*  proj_pad = (float*)(ws + 28672);    // 80*260 floats (83200 B)

    hipMemsetAsync(d_ws, 0, 28672, stream);     // zero s_buf + bn bins

    k_prep<<<(MM*260 + 255)/256, 256, 0, stream>>>(proj_w, proj_pad);

    dim3 g1(NN*FF, 2);
    k_beam_s<<<g1, 256, 0, stream>>>(x_real, x_imag, wq_r, wq_i, wk_r, wk_i, s_buf);

    k_softmax<<<1, 64, 0, stream>>>(s_buf, w_buf);

    dim3 g3(NN, 125);
    k_vproj<<<g3, 256, 0, stream>>>(x_real, x_imag, wv_r, wv_i, w_buf, proj_pad,
                                    out, bn_sum, bn_sumsq);

    k_bnprep<<<1, 128, 0, stream>>>(bn_sum, bn_sumsq, bn_gamma, bn_beta, scale, shift);

    k_bnapply<<<(NN*TT*MM/4 + 255)/256, 256, 0, stream>>>(out, scale, shift);
}

// Round 5
// 110.517 us; speedup vs baseline: 2.6378x; 1.1720x over previous
//
#include <hip/hip_runtime.h>
#include <math.h>

#define NN 8
#define CC 4
#define FF 257
#define TT 2000
#define BB 8
#define MM 80
#define EPSF 1e-5f
#define VSTR 260   // stride 260: 16B-aligned rows (260%4==0), bank offset 4/row -> worst 2-way (free)
#define T4N 500    // TT/4

typedef float v2f __attribute__((ext_vector_type(2)));

__device__ __forceinline__ float fsqrt_fast(float x) { return __builtin_amdgcn_sqrtf(x); }
__device__ __forceinline__ float flog_fast(float x)  { return __builtin_amdgcn_logf(x) * 0.69314718055994531f; }
__device__ __forceinline__ v2f sqrt2(v2f m) {
    v2f r; r.x = __builtin_amdgcn_sqrtf(m.x); r.y = __builtin_amdgcn_sqrtf(m.y); return r;
}

// ---------------- kernel 1: beamform q,k and reduce s partials ----------------
// grid (NN*FF, 2), block 256. Each thread: 4 consecutive t via float4, pk-math over t-pairs.
__global__ __launch_bounds__(256) void k_beam_s(
    const float* __restrict__ xr_g, const float* __restrict__ xi_g,
    const float* __restrict__ wq_r, const float* __restrict__ wq_i,
    const float* __restrict__ wk_r, const float* __restrict__ wk_i,
    float* __restrict__ s_buf)
{
    int nf = blockIdx.x;
    int n = nf / FF, f = nf % FF;
    int t4 = blockIdx.y * 256 + threadIdx.x;

    float part[BB];
#pragma unroll
    for (int b = 0; b < BB; ++b) part[b] = 0.f;

    if (t4 < T4N) {
        const float* xr_base = xr_g + ((size_t)(n*CC)*FF + f) * TT + t4*4;
        const float* xi_base = xi_g + ((size_t)(n*CC)*FF + f) * TT + t4*4;
        v2f xr2[CC][2], xi2[CC][2];
#pragma unroll
        for (int c = 0; c < CC; ++c) {
            float4 r4 = *reinterpret_cast<const float4*>(xr_base + (size_t)c*FF*TT);
            float4 i4 = *reinterpret_cast<const float4*>(xi_base + (size_t)c*FF*TT);
            xr2[c][0].x = r4.x; xr2[c][0].y = r4.y; xr2[c][1].x = r4.z; xr2[c][1].y = r4.w;
            xi2[c][0].x = i4.x; xi2[c][0].y = i4.y; xi2[c][1].x = i4.z; xi2[c][1].y = i4.w;
        }

        const float4 qr4 = *reinterpret_cast<const float4*>(&wq_r[f*CC]);  // f block-uniform -> s_load
        const float4 qi4 = *reinterpret_cast<const float4*>(&wq_i[f*CC]);

        v2f qq[2];
#pragma unroll
        for (int p = 0; p < 2; ++p) {
            v2f qr = xr2[0][p]*qr4.x + xr2[1][p]*qr4.y + xr2[2][p]*qr4.z + xr2[3][p]*qr4.w
                   - xi2[0][p]*qi4.x - xi2[1][p]*qi4.y - xi2[2][p]*qi4.z - xi2[3][p]*qi4.w;
            v2f qi = xi2[0][p]*qr4.x + xi2[1][p]*qr4.y + xi2[2][p]*qr4.z + xi2[3][p]*qr4.w
                   + xr2[0][p]*qi4.x + xr2[1][p]*qi4.y + xr2[2][p]*qi4.z + xr2[3][p]*qi4.w;
            qq[p] = qr*qr + qi*qi + EPSF;
        }

#pragma unroll
        for (int b = 0; b < BB; ++b) {
            const float4 wr4 = *reinterpret_cast<const float4*>(&wk_r[(f*BB + b)*CC]);
            const float4 wi4 = *reinterpret_cast<const float4*>(&wk_i[(f*BB + b)*CC]);
            v2f acc; acc.x = 0.f; acc.y = 0.f;
#pragma unroll
            for (int p = 0; p < 2; ++p) {
                v2f kr = xr2[0][p]*wr4.x + xr2[1][p]*wr4.y + xr2[2][p]*wr4.z + xr2[3][p]*wr4.w
                       - xi2[0][p]*wi4.x - xi2[1][p]*wi4.y - xi2[2][p]*wi4.z - xi2[3][p]*wi4.w;
                v2f ki = xi2[0][p]*wr4.x + xi2[1][p]*wr4.y + xi2[2][p]*wr4.z + xi2[3][p]*wr4.w
                       + xr2[0][p]*wi4.x + xr2[1][p]*wi4.y + xr2[2][p]*wi4.z + xr2[3][p]*wi4.w;
                v2f kk = kr*kr + ki*ki + EPSF;
                acc += sqrt2(qq[p] * kk);   // sqrt(qq)*sqrt(kk) fused
            }
            part[b] = acc.x + acc.y;
        }
    }

    __shared__ float red[4][BB];
    int lane = threadIdx.x & 63, wv = threadIdx.x >> 6;
#pragma unroll
    for (int b = 0; b < BB; ++b) {
        float v = part[b];
#pragma unroll
        for (int m = 32; m >= 1; m >>= 1) v += __shfl_xor(v, m);
        if (lane == 0) red[wv][b] = v;
    }
    __syncthreads();
    if (threadIdx.x < BB) {
        float v = red[0][threadIdx.x] + red[1][threadIdx.x]
                + red[2][threadIdx.x] + red[3][threadIdx.x];
        int bin = (blockIdx.x * 2 + blockIdx.y) & 15;
        atomicAdd(&s_buf[bin*64 + n*BB + threadIdx.x], v);
    }
}

// ---------------- kernel 2: softmax over B per n (sums 16 bins) ----------------
__global__ void k_softmax(const float* __restrict__ s_buf, float* __restrict__ w_buf)
{
    int tid = threadIdx.x;
    if (tid < NN*BB) {
        float v = 0.f;
#pragma unroll
        for (int j = 0; j < 16; ++j) v += s_buf[j*64 + tid];
        v *= (1.0f / TT);
        float mx = v;
#pragma unroll
        for (int m = 4; m >= 1; m >>= 1) mx = fmaxf(mx, __shfl_xor(mx, m));
        float e = expf(v - mx);
        float sm = e;
#pragma unroll
        for (int m = 4; m >= 1; m >>= 1) sm += __shfl_xor(sm, m);
        w_buf[tid] = e / sm;
    }
}

// ---------------- kernel 2b: repack proj_w into padded stride-260 ----------------
__global__ void k_prep(const float* __restrict__ proj_w, float* __restrict__ proj_pad)
{
    int i = blockIdx.x * 256 + threadIdx.x;
    if (i < MM * 260) {
        int m = i / 260, f = i % 260;
        proj_pad[i] = (f < FF) ? proj_w[m*FF + f] : 0.f;
    }
}

// ---------------- kernel 3 (FUSED): v from x -> LDS, project, relu, log, BN partials ----
// grid (NN, 125), block 256. t-tile = 16 (125*16 = 2000, no tail).
// Fill: (t4s = tid&3, fbase = tid>>2), 4 clean iters f = fbase+64k (0..255); f=256 by 16-lane epilogue.
// Proj: (tl = tid&15, fg = tid>>4): 5 m per thread, pk-FMA over f-pairs, b128 LDS reads.
__global__ __launch_bounds__(256) void k_vproj(
    const float* __restrict__ xr_g, const float* __restrict__ xi_g,
    const float* __restrict__ wv_r, const float* __restrict__ wv_i,
    const float* __restrict__ w_buf, const float* __restrict__ proj_pad,
    float* __restrict__ out, double* __restrict__ bn_sum, double* __restrict__ bn_sumsq)
{
    __shared__ float v_lds[16 * VSTR];
    int n = blockIdx.x, chunk = blockIdx.y;
    int t0 = chunk * 16;
    int tid = threadIdx.x;

    float wn[BB];
#pragma unroll
    for (int b = 0; b < BB; ++b) wn[b] = w_buf[n*BB + b];   // n uniform -> scalar

    // zero pad columns f = 257..259
    if (tid < 64 && (tid & 3) < 3) {
        int t = tid >> 2, f = FF + (tid & 3);
        v_lds[t*VSTR + f] = 0.f;
    }

    int t4s = tid & 3;      // which float4 of the 16-t tile
    int fbase = tid >> 2;   // 0..63

#pragma unroll 1
    for (int k = 0; k < 4; ++k) {
        int f = fbase + 64*k;   // 0..255, no bounds check
        v2f xr2[CC][2], xi2[CC][2];
#pragma unroll
        for (int c = 0; c < CC; ++c) {
            size_t base = ((size_t)(n*CC + c)*FF + f)*TT + t0 + t4s*4;
            float4 r4 = *reinterpret_cast<const float4*>(xr_g + base);
            float4 i4 = *reinterpret_cast<const float4*>(xi_g + base);
            xr2[c][0].x = r4.x; xr2[c][0].y = r4.y; xr2[c][1].x = r4.z; xr2[c][1].y = r4.w;
            xi2[c][0].x = i4.x; xi2[c][0].y = i4.y; xi2[c][1].x = i4.z; xi2[c][1].y = i4.w;
        }

        v2f vo[2];
        vo[0].x = 0.f; vo[0].y = 0.f; vo[1].x = 0.f; vo[1].y = 0.f;
#pragma unroll
        for (int b = 0; b < BB; ++b) {
            const float4 wr4 = *reinterpret_cast<const float4*>(&wv_r[(f*BB + b)*CC]);
            const float4 wi4 = *reinterpret_cast<const float4*>(&wv_i[(f*BB + b)*CC]);
#pragma unroll
            for (int p = 0; p < 2; ++p) {
                v2f vr = xr2[0][p]*wr4.x + xr2[1][p]*wr4.y + xr2[2][p]*wr4.z + xr2[3][p]*wr4.w
                       - xi2[0][p]*wi4.x - xi2[1][p]*wi4.y - xi2[2][p]*wi4.z - xi2[3][p]*wi4.w;
                v2f vi = xi2[0][p]*wr4.x + xi2[1][p]*wr4.y + xi2[2][p]*wr4.z + xi2[3][p]*wr4.w
                       + xr2[0][p]*wi4.x + xr2[1][p]*wi4.y + xr2[2][p]*wi4.z + xr2[3][p]*wi4.w;
                vo[p] += wn[b] * sqrt2(vr*vr + vi*vi + EPSF);
            }
        }
        v_lds[(t4s*4 + 0)*VSTR + f] = vo[0].x;
        v_lds[(t4s*4 + 1)*VSTR + f] = vo[0].y;
        v_lds[(t4s*4 + 2)*VSTR + f] = vo[1].x;
        v_lds[(t4s*4 + 3)*VSTR + f] = vo[1].y;
    }

    // f = 256 epilogue: 16 lanes, one t each (scalar)
    if (tid < 16) {
        int t = t0 + tid;
        float xr[CC], xi[CC];
#pragma unroll
        for (int c = 0; c < CC; ++c) {
            size_t base = ((size_t)(n*CC + c)*FF + 256)*TT + t;
            xr[c] = xr_g[base];
            xi[c] = xi_g[base];
        }
        float v = 0.f;
#pragma unroll
        for (int b = 0; b < BB; ++b) {
            const float4 wr4 = *reinterpret_cast<const float4*>(&wv_r[(256*BB + b)*CC]);
            const float4 wi4 = *reinterpret_cast<const float4*>(&wv_i[(256*BB + b)*CC]);
            float vr = xr[0]*wr4.x + xr[1]*wr4.y + xr[2]*wr4.z + xr[3]*wr4.w
                     - xi[0]*wi4.x - xi[1]*wi4.y - xi[2]*wi4.z - xi[3]*wi4.w;
            float vi = xi[0]*wr4.x + xi[1]*wr4.y + xi[2]*wr4.z + xi[3]*wr4.w
                     + xr[0]*wi4.x + xr[1]*wi4.y + xr[2]*wi4.z + xr[3]*wi4.w;
            v += wn[b] * fsqrt_fast(vr*vr + vi*vi + EPSF);
        }
        v_lds[tid*VSTR + 256] = v;
    }
    __syncthreads();

    // ---- proj stage (pk-FMA, b128 LDS reads) ----
    int tl = tid & 15, fg = tid >> 4;
    v2f acc2[5];
#pragma unroll
    for (int j = 0; j < 5; ++j) { acc2[j].x = 0.f; acc2[j].y = 0.f; }
    const float* pp = proj_pad + fg * 5 * 260;
#pragma unroll 4
    for (int f4 = 0; f4 < 260; f4 += 4) {
        float4 vv = *reinterpret_cast<const float4*>(&v_lds[tl*VSTR + f4]);  // 16B aligned
        v2f v0, v1;
        v0.x = vv.x; v0.y = vv.y; v1.x = vv.z; v1.y = vv.w;
#pragma unroll
        for (int j = 0; j < 5; ++j) {
            float4 p = *reinterpret_cast<const float4*>(&pp[j*260 + f4]);
            v2f p0, p1; p0.x = p.x; p0.y = p.y; p1.x = p.z; p1.y = p.w;
            acc2[j] += v0*p0 + v1*p1;
        }
    }

    int t = t0 + tl;
    int bin = chunk & 15;
#pragma unroll
    for (int j = 0; j < 5; ++j) {
        int m = fg*5 + j;
        float r = flog_fast(fmaxf(acc2[j].x + acc2[j].y, 0.f) + EPSF);
        float s1 = r, s2 = r*r;
#pragma unroll
        for (int msk = 8; msk >= 1; msk >>= 1) {
            s1 += __shfl_xor(s1, msk);
            s2 += __shfl_xor(s2, msk);
        }
        out[((size_t)n*TT + t)*MM + m] = r;
        if (tl == 0) {
            atomicAdd(&bn_sum[bin*MM + m], (double)s1);
            atomicAdd(&bn_sumsq[bin*MM + m], (double)s2);
        }
    }
}

// ---------------- kernel 4a: BN finalize (sums 16 bins) ----------------
__global__ void k_bnprep(const double* __restrict__ bn_sum, const double* __restrict__ bn_sumsq,
                         const float* __restrict__ gamma, const float* __restrict__ beta,
                         float* __restrict__ scale, float* __restrict__ shift)
{
    int m = threadIdx.x;
    if (m < MM) {
        double s = 0.0, q = 0.0;
#pragma unroll
        for (int j = 0; j < 16; ++j) { s += bn_sum[j*MM + m]; q += bn_sumsq[j*MM + m]; }
        double inv = 1.0 / (double)(NN * TT);
        double mu = s * inv;
        double var = q * inv - mu * mu;
        float sc = gamma[m] * rsqrtf((float)var + EPSF);
        scale[m] = sc;
        shift[m] = beta[m] - (float)mu * sc;
    }
}

// ---------------- kernel 4b: BN apply in-place (float4) ----------------
__global__ __launch_bounds__(256) void k_bnapply(float* __restrict__ out,
                                                 const float* __restrict__ scale,
                                                 const float* __restrict__ shift)
{
    int i4 = blockIdx.x * 256 + threadIdx.x;
    if (i4 < NN*TT*MM/4) {
        float4 v = *reinterpret_cast<const float4*>(&out[i4*4]);
        int m = (i4*4) % MM;
        v.x = v.x*scale[m+0] + shift[m+0];
        v.y = v.y*scale[m+1] + shift[m+1];
        v.z = v.z*scale[m+2] + shift[m+2];
        v.w = v.w*scale[m+3] + shift[m+3];
        *reinterpret_cast<float4*>(&out[i4*4]) = v;
    }
}

extern "C" void kernel_launch(void* const* d_in, const int* in_sizes, int n_in,
                              void* d_out, int out_size, void* d_ws, size_t ws_size,
                              hipStream_t stream)
{
    const float* x_real   = (const float*)d_in[0];
    const float* x_imag   = (const float*)d_in[1];
    const float* wq_r     = (const float*)d_in[2];
    const float* wq_i     = (const float*)d_in[3];
    const float* wk_r     = (const float*)d_in[4];
    const float* wk_i     = (const float*)d_in[5];
    const float* wv_r     = (const float*)d_in[6];
    const float* wv_i     = (const float*)d_in[7];
    const float* proj_w   = (const float*)d_in[8];
    const float* bn_gamma = (const float*)d_in[9];
    const float* bn_beta  = (const float*)d_in[10];
    float* out = (float*)d_out;

    char* ws = (char*)d_ws;
    float*  s_buf    = (float*)(ws + 0);        // 16 bins x 64 floats (4096 B)
    float*  w_buf    = (float*)(ws + 4096);     // 64 floats
    float*  scale    = (float*)(ws + 4352);     // 80 floats
    float*  shift    = (float*)(ws + 4672);     // 80 floats
    double* bn_sum   = (double*)(ws + 8192);    // 16 bins x 80 doubles (10240 B)
    double* bn_sumsq = (double*)(ws + 18432);   // 16 bins x 80 doubles (10240 B)
    float*  proj_pad = (float*)(ws + 28672);    // 80*260 floats (83200 B)

    hipMemsetAsync(d_ws, 0, 28672, stream);     // zero s_buf + bn bins

    k_prep<<<(MM*260 + 255)/256, 256, 0, stream>>>(proj_w, proj_pad);

    dim3 g1(NN*FF, 2);
    k_beam_s<<<g1, 256, 0, stream>>>(x_real, x_imag, wq_r, wq_i, wk_r, wk_i, s_buf);

    k_softmax<<<1, 64, 0, stream>>>(s_buf, w_buf);

    dim3 g3(NN, 125);
    k_vproj<<<g3, 256, 0, stream>>>(x_real, x_imag, wv_r, wv_i, w_buf, proj_pad,
                                    out, bn_sum, bn_sumsq);

    k_bnprep<<<1, 128, 0, stream>>>(bn_sum, bn_sumsq, bn_gamma, bn_beta, scale, shift);

    k_bnapply<<<(NN*TT*MM/4 + 255)/256, 256, 0, stream>>>(out, scale, shift);
}

// Round 6
// 110.460 us; speedup vs baseline: 2.6391x; 1.0005x over previous
//
#include <hip/hip_runtime.h>
#include <math.h>

#define NN 8
#define CC 4
#define FF 257
#define TT 2000
#define BB 8
#define MM 80
#define EPSF 1e-5f
#define VSTR 260   // stride 260: 16B-aligned rows (260%4==0), bank offset 4/row -> worst 2-way (free)
#define T4N 500    // TT/4

typedef float v2f __attribute__((ext_vector_type(2)));

__device__ __forceinline__ float fsqrt_fast(float x) { return __builtin_amdgcn_sqrtf(x); }
__device__ __forceinline__ float flog_fast(float x)  { return __builtin_amdgcn_logf(x) * 0.69314718055994531f; }
__device__ __forceinline__ v2f sqrt2(v2f m) {
    v2f r; r.x = __builtin_amdgcn_sqrtf(m.x); r.y = __builtin_amdgcn_sqrtf(m.y); return r;
}

// ---------------- kernel 1: beamform q,k and reduce s partials ----------------
// grid (NN*FF, 2), block 256. Each thread: 4 consecutive t via float4, pk-math over t-pairs.
__global__ __launch_bounds__(256) void k_beam_s(
    const float* __restrict__ xr_g, const float* __restrict__ xi_g,
    const float* __restrict__ wq_r, const float* __restrict__ wq_i,
    const float* __restrict__ wk_r, const float* __restrict__ wk_i,
    float* __restrict__ s_buf)
{
    int nf = blockIdx.x;
    int n = nf / FF, f = nf % FF;
    int t4 = blockIdx.y * 256 + threadIdx.x;

    float part[BB];
#pragma unroll
    for (int b = 0; b < BB; ++b) part[b] = 0.f;

    if (t4 < T4N) {
        const float* xr_base = xr_g + ((size_t)(n*CC)*FF + f) * TT + t4*4;
        const float* xi_base = xi_g + ((size_t)(n*CC)*FF + f) * TT + t4*4;
        v2f xr2[CC][2], xi2[CC][2];
#pragma unroll
        for (int c = 0; c < CC; ++c) {
            float4 r4 = *reinterpret_cast<const float4*>(xr_base + (size_t)c*FF*TT);
            float4 i4 = *reinterpret_cast<const float4*>(xi_base + (size_t)c*FF*TT);
            xr2[c][0].x = r4.x; xr2[c][0].y = r4.y; xr2[c][1].x = r4.z; xr2[c][1].y = r4.w;
            xi2[c][0].x = i4.x; xi2[c][0].y = i4.y; xi2[c][1].x = i4.z; xi2[c][1].y = i4.w;
        }

        const float4 qr4 = *reinterpret_cast<const float4*>(&wq_r[f*CC]);  // f block-uniform -> s_load
        const float4 qi4 = *reinterpret_cast<const float4*>(&wq_i[f*CC]);

        v2f qq[2];
#pragma unroll
        for (int p = 0; p < 2; ++p) {
            v2f qr = xr2[0][p]*qr4.x + xr2[1][p]*qr4.y + xr2[2][p]*qr4.z + xr2[3][p]*qr4.w
                   - xi2[0][p]*qi4.x - xi2[1][p]*qi4.y - xi2[2][p]*qi4.z - xi2[3][p]*qi4.w;
            v2f qi = xi2[0][p]*qr4.x + xi2[1][p]*qr4.y + xi2[2][p]*qr4.z + xi2[3][p]*qr4.w
                   + xr2[0][p]*qi4.x + xr2[1][p]*qi4.y + xr2[2][p]*qi4.z + xr2[3][p]*qi4.w;
            qq[p] = qr*qr + qi*qi + EPSF;
        }

#pragma unroll
        for (int b = 0; b < BB; ++b) {
            const float4 wr4 = *reinterpret_cast<const float4*>(&wk_r[(f*BB + b)*CC]);
            const float4 wi4 = *reinterpret_cast<const float4*>(&wk_i[(f*BB + b)*CC]);
            v2f acc; acc.x = 0.f; acc.y = 0.f;
#pragma unroll
            for (int p = 0; p < 2; ++p) {
                v2f kr = xr2[0][p]*wr4.x + xr2[1][p]*wr4.y + xr2[2][p]*wr4.z + xr2[3][p]*wr4.w
                       - xi2[0][p]*wi4.x - xi2[1][p]*wi4.y - xi2[2][p]*wi4.z - xi2[3][p]*wi4.w;
                v2f ki = xi2[0][p]*wr4.x + xi2[1][p]*wr4.y + xi2[2][p]*wr4.z + xi2[3][p]*wr4.w
                       + xr2[0][p]*wi4.x + xr2[1][p]*wi4.y + xr2[2][p]*wi4.z + xr2[3][p]*wi4.w;
                v2f kk = kr*kr + ki*ki + EPSF;
                acc += sqrt2(qq[p] * kk);   // sqrt(qq)*sqrt(kk) fused
            }
            part[b] = acc.x + acc.y;
        }
    }

    __shared__ float red[4][BB];
    int lane = threadIdx.x & 63, wv = threadIdx.x >> 6;
#pragma unroll
    for (int b = 0; b < BB; ++b) {
        float v = part[b];
#pragma unroll
        for (int m = 32; m >= 1; m >>= 1) v += __shfl_xor(v, m);
        if (lane == 0) red[wv][b] = v;
    }
    __syncthreads();
    if (threadIdx.x < BB) {
        float v = red[0][threadIdx.x] + red[1][threadIdx.x]
                + red[2][threadIdx.x] + red[3][threadIdx.x];
        int bin = (blockIdx.x * 2 + blockIdx.y) & 15;
        atomicAdd(&s_buf[bin*64 + n*BB + threadIdx.x], v);
    }
}

// ---------------- kernel 2: softmax over B per n (sums 16 bins) ----------------
__global__ void k_softmax(const float* __restrict__ s_buf, float* __restrict__ w_buf)
{
    int tid = threadIdx.x;
    if (tid < NN*BB) {
        float v = 0.f;
#pragma unroll
        for (int j = 0; j < 16; ++j) v += s_buf[j*64 + tid];
        v *= (1.0f / TT);
        float mx = v;
#pragma unroll
        for (int m = 4; m >= 1; m >>= 1) mx = fmaxf(mx, __shfl_xor(mx, m));
        float e = expf(v - mx);
        float sm = e;
#pragma unroll
        for (int m = 4; m >= 1; m >>= 1) sm += __shfl_xor(sm, m);
        w_buf[tid] = e / sm;
    }
}

// ---------------- kernel 2b: repack proj_w into padded stride-260 ----------------
__global__ void k_prep(const float* __restrict__ proj_w, float* __restrict__ proj_pad)
{
    int i = blockIdx.x * 256 + threadIdx.x;
    if (i < MM * 260) {
        int m = i / 260, f = i % 260;
        proj_pad[i] = (f < FF) ? proj_w[m*FF + f] : 0.f;
    }
}

// ---------------- kernel 3 (FUSED): v from x -> LDS, project, relu, log, BN partials ----
// grid (NN, 125), block 256. t-tile = 16 (125*16 = 2000, no tail).
// Fill: (t4s = tid&3, fbase = tid>>2), 4 iters f = fbase+64k (0..255) unroll-2 for load ILP;
//       f=256 handled FIRST (16-lane scalar) so its loads overlap the main loop.
// Proj: (tl = tid&15, fg = tid>>4): 5 m per thread, pk-FMA over f-pairs, b128 LDS reads.
__global__ __launch_bounds__(256, 4) void k_vproj(
    const float* __restrict__ xr_g, const float* __restrict__ xi_g,
    const float* __restrict__ wv_r, const float* __restrict__ wv_i,
    const float* __restrict__ w_buf, const float* __restrict__ proj_pad,
    float* __restrict__ out, double* __restrict__ bn_sum, double* __restrict__ bn_sumsq)
{
    __shared__ float v_lds[16 * VSTR];
    int n = blockIdx.x, chunk = blockIdx.y;
    int t0 = chunk * 16;
    int tid = threadIdx.x;

    float wn[BB];
#pragma unroll
    for (int b = 0; b < BB; ++b) wn[b] = w_buf[n*BB + b];   // n uniform -> scalar

    // zero pad columns f = 257..259
    if (tid < 64 && (tid & 3) < 3) {
        int t = tid >> 2, f = FF + (tid & 3);
        v_lds[t*VSTR + f] = 0.f;
    }

    // f = 256 column FIRST: 16 lanes, one t each (scalar) — loads overlap main loop
    if (tid < 16) {
        int t = t0 + tid;
        float xr[CC], xi[CC];
#pragma unroll
        for (int c = 0; c < CC; ++c) {
            size_t base = ((size_t)(n*CC + c)*FF + 256)*TT + t;
            xr[c] = xr_g[base];
            xi[c] = xi_g[base];
        }
        float v = 0.f;
#pragma unroll
        for (int b = 0; b < BB; ++b) {
            const float4 wr4 = *reinterpret_cast<const float4*>(&wv_r[(256*BB + b)*CC]);
            const float4 wi4 = *reinterpret_cast<const float4*>(&wv_i[(256*BB + b)*CC]);
            float vr = xr[0]*wr4.x + xr[1]*wr4.y + xr[2]*wr4.z + xr[3]*wr4.w
                     - xi[0]*wi4.x - xi[1]*wi4.y - xi[2]*wi4.z - xi[3]*wi4.w;
            float vi = xi[0]*wr4.x + xi[1]*wr4.y + xi[2]*wr4.z + xi[3]*wr4.w
                     + xr[0]*wi4.x + xr[1]*wi4.y + xr[2]*wi4.z + xr[3]*wi4.w;
            v += wn[b] * fsqrt_fast(vr*vr + vi*vi + EPSF);
        }
        v_lds[tid*VSTR + 256] = v;
    }

    int t4s = tid & 3;      // which float4 of the 16-t tile
    int fbase = tid >> 2;   // 0..63

#pragma unroll 2
    for (int k = 0; k < 4; ++k) {
        int f = fbase + 64*k;   // 0..255, no bounds check
        v2f xr2[CC][2], xi2[CC][2];
#pragma unroll
        for (int c = 0; c < CC; ++c) {
            size_t base = ((size_t)(n*CC + c)*FF + f)*TT + t0 + t4s*4;
            float4 r4 = *reinterpret_cast<const float4*>(xr_g + base);
            float4 i4 = *reinterpret_cast<const float4*>(xi_g + base);
            xr2[c][0].x = r4.x; xr2[c][0].y = r4.y; xr2[c][1].x = r4.z; xr2[c][1].y = r4.w;
            xi2[c][0].x = i4.x; xi2[c][0].y = i4.y; xi2[c][1].x = i4.z; xi2[c][1].y = i4.w;
        }

        v2f vo[2];
        vo[0].x = 0.f; vo[0].y = 0.f; vo[1].x = 0.f; vo[1].y = 0.f;
#pragma unroll
        for (int b = 0; b < BB; ++b) {
            const float4 wr4 = *reinterpret_cast<const float4*>(&wv_r[(f*BB + b)*CC]);
            const float4 wi4 = *reinterpret_cast<const float4*>(&wv_i[(f*BB + b)*CC]);
#pragma unroll
            for (int p = 0; p < 2; ++p) {
                v2f vr = xr2[0][p]*wr4.x + xr2[1][p]*wr4.y + xr2[2][p]*wr4.z + xr2[3][p]*wr4.w
                       - xi2[0][p]*wi4.x - xi2[1][p]*wi4.y - xi2[2][p]*wi4.z - xi2[3][p]*wi4.w;
                v2f vi = xi2[0][p]*wr4.x + xi2[1][p]*wr4.y + xi2[2][p]*wr4.z + xi2[3][p]*wr4.w
                       + xr2[0][p]*wi4.x + xr2[1][p]*wi4.y + xr2[2][p]*wi4.z + xr2[3][p]*wi4.w;
                vo[p] += wn[b] * sqrt2(vr*vr + vi*vi + EPSF);
            }
        }
        v_lds[(t4s*4 + 0)*VSTR + f] = vo[0].x;
        v_lds[(t4s*4 + 1)*VSTR + f] = vo[0].y;
        v_lds[(t4s*4 + 2)*VSTR + f] = vo[1].x;
        v_lds[(t4s*4 + 3)*VSTR + f] = vo[1].y;
    }
    __syncthreads();

    // ---- proj stage (pk-FMA, b128 LDS reads) ----
    int tl = tid & 15, fg = tid >> 4;
    v2f acc2[5];
#pragma unroll
    for (int j = 0; j < 5; ++j) { acc2[j].x = 0.f; acc2[j].y = 0.f; }
    const float* pp = proj_pad + fg * 5 * 260;
#pragma unroll 4
    for (int f4 = 0; f4 < 260; f4 += 4) {
        float4 vv = *reinterpret_cast<const float4*>(&v_lds[tl*VSTR + f4]);  // 16B aligned
        v2f v0, v1;
        v0.x = vv.x; v0.y = vv.y; v1.x = vv.z; v1.y = vv.w;
#pragma unroll
        for (int j = 0; j < 5; ++j) {
            float4 p = *reinterpret_cast<const float4*>(&pp[j*260 + f4]);
            v2f p0, p1; p0.x = p.x; p0.y = p.y; p1.x = p.z; p1.y = p.w;
            acc2[j] += v0*p0 + v1*p1;
        }
    }

    int t = t0 + tl;
    int bin = chunk & 15;
#pragma unroll
    for (int j = 0; j < 5; ++j) {
        int m = fg*5 + j;
        float r = flog_fast(fmaxf(acc2[j].x + acc2[j].y, 0.f) + EPSF);
        float s1 = r, s2 = r*r;
#pragma unroll
        for (int msk = 8; msk >= 1; msk >>= 1) {
            s1 += __shfl_xor(s1, msk);
            s2 += __shfl_xor(s2, msk);
        }
        out[((size_t)n*TT + t)*MM + m] = r;
        if (tl == 0) {
            atomicAdd(&bn_sum[bin*MM + m], (double)s1);
            atomicAdd(&bn_sumsq[bin*MM + m], (double)s2);
        }
    }
}

// ---------------- kernel 4a: BN finalize (sums 16 bins) ----------------
__global__ void k_bnprep(const double* __restrict__ bn_sum, const double* __restrict__ bn_sumsq,
                         const float* __restrict__ gamma, const float* __restrict__ beta,
                         float* __restrict__ scale, float* __restrict__ shift)
{
    int m = threadIdx.x;
    if (m < MM) {
        double s = 0.0, q = 0.0;
#pragma unroll
        for (int j = 0; j < 16; ++j) { s += bn_sum[j*MM + m]; q += bn_sumsq[j*MM + m]; }
        double inv = 1.0 / (double)(NN * TT);
        double mu = s * inv;
        double var = q * inv - mu * mu;
        float sc = gamma[m] * rsqrtf((float)var + EPSF);
        scale[m] = sc;
        shift[m] = beta[m] - (float)mu * sc;
    }
}

// ---------------- kernel 4b: BN apply in-place (float4) ----------------
__global__ __launch_bounds__(256) void k_bnapply(float* __restrict__ out,
                                                 const float* __restrict__ scale,
                                                 const float* __restrict__ shift)
{
    int i4 = blockIdx.x * 256 + threadIdx.x;
    if (i4 < NN*TT*MM/4) {
        float4 v = *reinterpret_cast<const float4*>(&out[i4*4]);
        int m = (i4*4) % MM;
        v.x = v.x*scale[m+0] + shift[m+0];
        v.y = v.y*scale[m+1] + shift[m+1];
        v.z = v.z*scale[m+2] + shift[m+2];
        v.w = v.w*scale[m+3] + shift[m+3];
        *reinterpret_cast<float4*>(&out[i4*4]) = v;
    }
}

extern "C" void kernel_launch(void* const* d_in, const int* in_sizes, int n_in,
                              void* d_out, int out_size, void* d_ws, size_t ws_size,
                              hipStream_t stream)
{
    const float* x_real   = (const float*)d_in[0];
    const float* x_imag   = (const float*)d_in[1];
    const float* wq_r     = (const float*)d_in[2];
    const float* wq_i     = (const float*)d_in[3];
    const float* wk_r     = (const float*)d_in[4];
    const float* wk_i     = (const float*)d_in[5];
    const float* wv_r     = (const float*)d_in[6];
    const float* wv_i     = (const float*)d_in[7];
    const float* proj_w   = (const float*)d_in[8];
    const float* bn_gamma = (const float*)d_in[9];
    const float* bn_beta  = (const float*)d_in[10];
    float* out = (float*)d_out;

    char* ws = (char*)d_ws;
    float*  s_buf    = (float*)(ws + 0);        // 16 bins x 64 floats (4096 B)
    float*  w_buf    = (float*)(ws + 4096);     // 64 floats
    float*  scale    = (float*)(ws + 4352);     // 80 floats
    float*  shift    = (float*)(ws + 4672);     // 80 floats
    double* bn_sum   = (double*)(ws + 8192);    // 16 bins x 80 doubles (10240 B)
    double* bn_sumsq = (double*)(ws + 18432);   // 16 bins x 80 doubles (10240 B)
    float*  proj_pad = (float*)(ws + 28672);    // 80*260 floats (83200 B)

    hipMemsetAsync(d_ws, 0, 28672, stream);     // zero s_buf + bn bins

    k_prep<<<(MM*260 + 255)/256, 256, 0, stream>>>(proj_w, proj_pad);

    dim3 g1(NN*FF, 2);
    k_beam_s<<<g1, 256, 0, stream>>>(x_real, x_imag, wq_r, wq_i, wk_r, wk_i, s_buf);

    k_softmax<<<1, 64, 0, stream>>>(s_buf, w_buf);

    dim3 g3(NN, 125);
    k_vproj<<<g3, 256, 0, stream>>>(x_real, x_imag, wv_r, wv_i, w_buf, proj_pad,
                                    out, bn_sum, bn_sumsq);

    k_bnprep<<<1, 128, 0, stream>>>(bn_sum, bn_sumsq, bn_gamma, bn_beta, scale, shift);

    k_bnapply<<<(NN*TT*MM/4 + 255)/256, 256, 0, stream>>>(out, scale, shift);
}